// Round 9
// baseline (815.832 us; speedup 1.0000x reference)
//
#include <hip/hip_runtime.h>
#include <hip/hip_cooperative_groups.h>

namespace cg = cooperative_groups;

#define N_RELS 16
#define N_BASES 8
#define HD 128
#define ROWS 32

typedef __attribute__((ext_vector_type(8))) short bf16x8;
typedef __attribute__((ext_vector_type(4))) float floatx4;
typedef __attribute__((ext_vector_type(2))) float floatx2;

__device__ __forceinline__ short bf16rn(float f) {
    union { float f; unsigned u; } v; v.f = f;
    unsigned u = v.u;
    unsigned r = (u + 0x7fffu + ((u >> 16) & 1u)) >> 16;
    return (short)r;
}

__device__ __forceinline__ unsigned packbf2(floatx2 a) {
    return ((unsigned)(unsigned short)bf16rn(a.y) << 16) | (unsigned short)bf16rn(a.x);
}

// ---------------- ONE cooperative setup kernel ----------------
// Replaces memset + setup_fused + scan_partial + scan_fixup + scatter_dst (5 dispatches
// whose fixed launch/gap overhead ~20us each dominated the non-tile time: total minus
// tiles was 165+-4us across rounds 2-8 regardless of setup structure).
// Phases (grid.sync between dependent ones):
//  P0: zero cnt | pack h->bf16 | V->MFMA-frags     (independent, one pass)
//  P1: histogram over dst
//  P2: 3-phase exclusive scan of cnt[0..N) (wave-scan per 64-chunk; single-wave
//      block-sum scan; fixup writes row_ptr+cursor)
//  P3: scatter edges into dst-sorted edata (atomic cursor; per-bucket order
//      nondeterministic, tolerated since round 0)

__global__ void setup_all(const float* __restrict__ h, unsigned* __restrict__ hb,
                          const float* __restrict__ V1, const float* __restrict__ V2,
                          short* __restrict__ Vf,
                          const int* __restrict__ dst, const int* __restrict__ src,
                          const int* __restrict__ et, const float* __restrict__ norm,
                          int* __restrict__ cnt, int* __restrict__ row_ptr,
                          int* __restrict__ cursor, int* __restrict__ bsum,
                          int* __restrict__ bpre, int2* __restrict__ edata,
                          int N, int E) {
    cg::grid_group grid = cg::this_grid();
    const int tid = threadIdx.x;
    const int gid = blockIdx.x;
    const int gtid = gid * blockDim.x + tid;
    const int GSZ = gridDim.x * blockDim.x;
    const int lane = tid & 63;
    const int nchunk = (N + 63) >> 6;   // 782

    // ---- P0: zero cnt | pack h (float4 -> 2x bf16x2) | V frags
    for (int i = gtid; i < N; i += GSZ) cnt[i] = 0;
    const int n4 = N * 32;   // float4 count
    for (int i = gtid; i < n4; i += GSZ) {
        float4 v = ((const float4*)h)[i];
        uint2 o;
        o.x = ((unsigned)(unsigned short)bf16rn(v.y) << 16) | (unsigned short)bf16rn(v.x);
        o.y = ((unsigned)(unsigned short)bf16rn(v.w) << 16) | (unsigned short)bf16rn(v.z);
        ((uint2*)hb)[i] = o;
    }
    for (int x = gtid; x < 16 * 16384; x += GSZ) {
        int blk = x >> 14, e = x & 16383;
        const float* V = ((blk & 8) ? V2 : V1) + (size_t)(blk & 7) * 16384;
        float w = V[e];
        int k = e >> 7, n = e & 127;
        int kk = k >> 5, q = (k >> 3) & 3, j = k & 7;
        int ln = q * 16 + (n & 15);
        int idx = ((kk * 8 + (n >> 4)) * 64 + ln) * 8 + j;
        Vf[(size_t)blk * 16384 + idx] = bf16rn(w);
    }
    grid.sync();

    // ---- P1: histogram
    for (int i = gtid; i < E; i += GSZ) atomicAdd(&cnt[dst[i]], 1);
    grid.sync();

    // ---- P2a: per-chunk wave scan (wave 0 of each block; chunk = 64 nodes)
    if (gid < nchunk && tid < 64) {
        int i = gid * 64 + lane;
        int v = (i < N) ? cnt[i] : 0;
        int incl = v;
#pragma unroll
        for (int o = 1; o < 64; o <<= 1) {
            int u = __shfl_up(incl, o, 64);
            if (lane >= o) incl += u;
        }
        if (i < N) row_ptr[i] = incl - v;          // local exclusive
        if (lane == 63) bsum[gid] = incl;          // chunk total
    }
    grid.sync();

    // ---- P2b: single-wave scan of chunk totals (782 values, carry loop)
    if (gid == 0 && tid < 64) {
        int carry = 0;
        for (int c0 = 0; c0 < nchunk; c0 += 64) {
            int c = c0 + lane;
            int v = (c < nchunk) ? bsum[c] : 0;
            int incl = v;
#pragma unroll
            for (int o = 1; o < 64; o <<= 1) {
                int u = __shfl_up(incl, o, 64);
                if (lane >= o) incl += u;
            }
            if (c < nchunk) bpre[c] = carry + incl - v;
            carry += __shfl(incl, 63, 64);
        }
    }
    grid.sync();

    // ---- P2c: fixup + cursor init + sentinel
    if (gid < nchunk && tid < 64) {
        int i = gid * 64 + lane;
        if (i < N) {
            int val = row_ptr[i] + bpre[gid];
            row_ptr[i] = val;
            cursor[i] = val;
        }
    }
    if (gtid == 0) row_ptr[N] = E;
    grid.sync();

    // ---- P3: scatter into dst-sorted order; pack (etype, src): src < 65536
    for (int i = gtid; i < E; i += GSZ) {
        int p = atomicAdd(&cursor[dst[i]], 1);
        edata[p] = make_int2((et[i] << 16) | src[i], __float_as_int(norm[i]));
    }
}

// ---------------- fused per-tile RGCN layer (round-4 winner, byte-identical) ----------------
// Block = 32 dst rows, 512 threads (8 waves). Phase A (quarter-wave row-parallel):
// quarter q of wave w owns dst row 4w+q; its 16 lanes cover that row's 128 cols as
// dwordx4 (lane l16 -> words 4*l16..4*l16+3). ONE gather instruction therefore carries
// 4 edges (one per quarter) -- 4x fewer serial round-trips than per-edge gathering,
// robust against compiler rescheduling (width, not depth). Trip count = max quad row
// length; idle slots gather a clamped-valid edge with nv=0. edata prefetched 2-deep
// via named ping-pong regs (no array copies -> no forced vmcnt drain). coef in LDS
// (per-quarter et), read as 2x ds_read_b128. Flush: no cross-lane reduce -- lane
// (q,l16) writes frag words Zs[b][l16>>2][l16&3][4w+q][0..3].
// Phase B: Z(32x1024) @ V(1024x128); B-frags from L2-resident Vf; wave = t-tile x 2 m.
// mode 0: store bf16(relu(acc+bias)); mode 1: store fp32(acc+bias).

__global__ __launch_bounds__(512, 4) void rgcn_tile(
    const unsigned* __restrict__ hb, const int2* __restrict__ edata,
    const int* __restrict__ row_ptr, const float* __restrict__ coef,
    const short* __restrict__ Vf, const float* __restrict__ bias,
    void* __restrict__ outp, int N, int E, int mode) {
    __shared__ __align__(16) unsigned Zs[N_BASES][4][4][ROWS + 1][4];  // 66 KB
    __shared__ __align__(16) float cofs[N_RELS * N_BASES];             // 512 B

    const int tid = threadIdx.x;
    const int wave = tid >> 6, lane = tid & 63;
    const int l16 = lane & 15;
    const int nb0 = blockIdx.x * ROWS;

    if (tid < N_RELS * N_BASES) cofs[tid] = coef[tid];
    __syncthreads();

    // quarter q of wave w owns local row r = tid>>4 (0..31)
    const int r = tid >> 4;
    const int node = nb0 + r;
    const int cn = (node < N) ? node : (N - 1);
    const int s = row_ptr[cn];
    const int len = (node < N) ? (row_ptr[cn + 1] - s) : 0;

    // wave-uniform trip count = max len over the wave's 4 quarters
    int mx = len;
    mx = max(mx, __shfl_xor(mx, 16, 64));
    mx = max(mx, __shfl_xor(mx, 32, 64));
    const int nG = __builtin_amdgcn_readfirstlane(mx);

    floatx2 acc[4][N_BASES] = {};   // [word c][base b], statically indexed only

    auto edix = [&](int j) { int ix = s + j; return (ix > E - 1) ? (E - 1) : ix; };
    auto gath = [&](int2 m) {
        return ((const uint4*)(hb + (size_t)(m.x & 0xffff) * 64))[l16];
    };
    auto procG = [&](int2 m, uint4 g, int j) {
        float nv = (j < len) ? __int_as_float(m.y) : 0.f;
        int ets = m.x >> 16;                               // always valid 0..15
        floatx4 c0 = *(const floatx4*)&cofs[ets * 8];      // ds_read_b128 x2
        floatx4 c1 = *(const floatx4*)&cofs[ets * 8 + 4];
        floatx2 v0, v1, v2, v3;
        v0.x = __uint_as_float(g.x << 16) * nv; v0.y = __uint_as_float(g.x & 0xffff0000u) * nv;
        v1.x = __uint_as_float(g.y << 16) * nv; v1.y = __uint_as_float(g.y & 0xffff0000u) * nv;
        v2.x = __uint_as_float(g.z << 16) * nv; v2.y = __uint_as_float(g.z & 0xffff0000u) * nv;
        v3.x = __uint_as_float(g.w << 16) * nv; v3.y = __uint_as_float(g.w & 0xffff0000u) * nv;
#pragma unroll
        for (int b = 0; b < N_BASES; b++) {
            float cw = (b < 4) ? c0[b & 3] : c1[b & 3];
            acc[0][b] = v0 * cw + acc[0][b];
            acc[1][b] = v1 * cw + acc[1][b];
            acc[2][b] = v2 * cw + acc[2][b];
            acc[3][b] = v3 * cw + acc[3][b];
        }
    };

    // 2-deep ping-pong: named regs only (register-array copies force vmcnt drains)
    int2 m0 = edata[edix(0)];
    uint4 g0 = gath(m0);
    int2 m1 = edata[edix(1)];

    int k = 0;
    for (; k + 2 <= nG; k += 2) {
        uint4 g1 = gath(m1);          // gather k+1 (m1 loaded >=1 iter ago)
        procG(m0, g0, k);             // waits g0 only (older in FIFO)
        m0 = edata[edix(k + 2)];
        g0 = gath(m0);                // gather k+2
        procG(m1, g1, k + 1);
        m1 = edata[edix(k + 3)];
    }
    if (k < nG) procG(m0, g0, k);     // nG-k <= 1

    // flush: lane (q,l16) owns row r, words 4*l16+c -> frag coords ((l16>>2),(l16&3),c)
    {
        uint4 w;
#pragma unroll
        for (int b = 0; b < N_BASES; b++) {
            w.x = packbf2(acc[0][b]);
            w.y = packbf2(acc[1][b]);
            w.z = packbf2(acc[2][b]);
            w.w = packbf2(acc[3][b]);
            *(uint4*)&Zs[b][l16 >> 2][l16 & 3][r][0] = w;
        }
    }
    __syncthreads();

    // ---- phase B: wave owns t-tile tt=wave, m-tiles {0,1}
    const int q = lane >> 4, cc = lane & 15;
    const int tt = wave;
    floatx4 ac0 = {}, ac1 = {};

#pragma unroll 2
    for (int b = 0; b < N_BASES; b++) {
#pragma unroll
        for (int kk = 0; kk < 4; kk++) {
            bf16x8 a = *(const bf16x8*)&Zs[b][kk][q][cc][0];
            bf16x8 am = *(const bf16x8*)&Zs[b][kk][q][16 + cc][0];
            bf16x8 B = *(const bf16x8*)(Vf + (size_t)b * 16384 +
                                        ((size_t)(kk * 8 + tt) * 64 + lane) * 8);
            ac0 = __builtin_amdgcn_mfma_f32_16x16x32_bf16(a, B, ac0, 0, 0, 0);
            ac1 = __builtin_amdgcn_mfma_f32_16x16x32_bf16(am, B, ac1, 0, 0, 0);
        }
    }

    // ---- epilogue: C/D layout col = tt*16+cc, row(m) = mi*16 + q*4+i
    float bv = bias[tt * 16 + cc];
    if (mode == 0) {
        unsigned short* o = (unsigned short*)outp;
#pragma unroll
        for (int mi = 0; mi < 2; mi++) {
            const floatx4& c = mi ? ac1 : ac0;
#pragma unroll
            for (int i = 0; i < 4; i++) {
                int nd = nb0 + mi * 16 + q * 4 + i;
                if (nd < N) {
                    float v = fmaxf(c[i] + bv, 0.f);
                    o[(size_t)nd * HD + tt * 16 + cc] = (unsigned short)bf16rn(v);
                }
            }
        }
    } else {
        float* o = (float*)outp;
#pragma unroll
        for (int mi = 0; mi < 2; mi++) {
            const floatx4& c = mi ? ac1 : ac0;
#pragma unroll
            for (int i = 0; i < 4; i++) {
                int nd = nb0 + mi * 16 + q * 4 + i;
                if (nd < N) o[(size_t)nd * HD + tt * 16 + cc] = c[i] + bv;
            }
        }
    }
}

// ---------------- launch ----------------

extern "C" void kernel_launch(void* const* d_in, const int* in_sizes, int n_in,
                              void* d_out, int out_size, void* d_ws, size_t ws_size,
                              hipStream_t stream) {
    const float* h     = (const float*)d_in[0];
    const float* norm  = (const float*)d_in[1];
    const int*   src   = (const int*)d_in[2];
    const int*   dst   = (const int*)d_in[3];
    const int*   etype = (const int*)d_in[4];
    const float* V1    = (const float*)d_in[5];
    const float* coef1 = (const float*)d_in[6];
    const float* bias1 = (const float*)d_in[7];
    const float* V2    = (const float*)d_in[8];
    const float* coef2 = (const float*)d_in[9];
    const float* bias2 = (const float*)d_in[10];
    const int N = in_sizes[0] / HD;   // 50000
    const int E = in_sizes[2];        // 640000
    float* out = (float*)d_out;
    (void)n_in; (void)out_size; (void)ws_size;

    char* ws = (char*)d_ws;
    size_t off = 0;
    auto alloc = [&](size_t bytes) {
        void* p = ws + off;
        off += (bytes + 255) & ~(size_t)255;
        return p;
    };
    short*    Vf      = (short*)alloc((size_t)16 * 16384 * sizeof(short));   // 512 KB
    unsigned* hb      = (unsigned*)alloc((size_t)N * 64 * sizeof(unsigned)); // 12.8 MB
    unsigned* h1b     = (unsigned*)alloc((size_t)N * 64 * sizeof(unsigned)); // 12.8 MB
    int2*     edata   = (int2*)alloc((size_t)E * sizeof(int2));
    int*      cnt     = (int*)alloc((size_t)N * sizeof(int));
    int*      row_ptr = (int*)alloc((size_t)(N + 1) * sizeof(int));
    int*      cursor  = (int*)alloc((size_t)N * sizeof(int));
    int*      bsum    = (int*)alloc(1024 * sizeof(int));
    int*      bpre    = (int*)alloc(1024 * sizeof(int));

    // one cooperative dispatch does: zero+pack+frags -> hist -> scan -> scatter
    {
        void* args[] = {
            (void*)&h, (void*)&hb, (void*)&V1, (void*)&V2, (void*)&Vf,
            (void*)&dst, (void*)&src, (void*)&etype, (void*)&norm,
            (void*)&cnt, (void*)&row_ptr, (void*)&cursor, (void*)&bsum,
            (void*)&bpre, (void*)&edata, (void*)&N, (void*)&E
        };
        hipLaunchCooperativeKernel((void*)setup_all, dim3(1024), dim3(256),
                                   args, 0, stream);
    }

    const int tiles = (N + ROWS - 1) / ROWS;   // 1563

    // layer 1: h1b = bf16(relu(bias1 + Z @ V1))
    rgcn_tile<<<tiles, 512, 0, stream>>>(hb, edata, row_ptr, coef1, Vf, bias1, h1b, N, E, 0);
    // layer 2: out = bias2 + Z(h1b) @ V2
    rgcn_tile<<<tiles, 512, 0, stream>>>(h1b, edata, row_ptr, coef2, Vf + (size_t)8 * 16384,
                                         bias2, out, N, E, 1);
}

// Round 10
// 305.221 us; speedup vs baseline: 2.6729x; 2.6729x over previous
//
#include <hip/hip_runtime.h>

#define N_RELS 16
#define N_BASES 8
#define HD 128
#define SCAN_B 1024
#define ROWS 32

typedef __attribute__((ext_vector_type(8))) short bf16x8;
typedef __attribute__((ext_vector_type(4))) float floatx4;
typedef __attribute__((ext_vector_type(2))) float floatx2;

__device__ __forceinline__ short bf16rn(float f) {
    union { float f; unsigned u; } v; v.f = f;
    unsigned u = v.u;
    unsigned r = (u + 0x7fffu + ((u >> 16) & 1u)) >> 16;
    return (short)r;
}

__device__ __forceinline__ unsigned packbf2(floatx2 a) {
    return ((unsigned)(unsigned short)bf16rn(a.y) << 16) | (unsigned short)bf16rn(a.x);
}

// ---------------- fused setup: pack h->bf16 | V->frags | dst histogram ----------------

__global__ void setup_fused(const float* __restrict__ h, unsigned* __restrict__ hb, int n4,
                            const float* __restrict__ V1, const float* __restrict__ V2,
                            short* __restrict__ Vf,
                            const int* __restrict__ dst, int E, int* __restrict__ cnt,
                            int packBlocks, int vBlocks) {
    int blk = blockIdx.x;
    if (blk < packBlocks) {
        int i = blk * blockDim.x + threadIdx.x;
        if (i < n4) {
            float4 v = ((const float4*)h)[i];
            uint2 o;
            o.x = ((unsigned)(unsigned short)bf16rn(v.y) << 16) | (unsigned short)bf16rn(v.x);
            o.y = ((unsigned)(unsigned short)bf16rn(v.w) << 16) | (unsigned short)bf16rn(v.z);
            ((uint2*)hb)[i] = o;
        }
        return;
    }
    blk -= packBlocks;
    if (blk < vBlocks) {
        // frag: lane holds B[n=lane&15][k=(lane>>4)*8+j]; idx = ((kk*8+t)*64+lane)*8+j
        const float* V = ((blk & 8) ? V2 : V1) + (size_t)(blk & 7) * 16384;
        size_t obase = (size_t)blk * 16384;
        for (int e = threadIdx.x; e < 16384; e += blockDim.x) {
            float w = V[e];
            int k = e >> 7, n = e & 127;
            int kk = k >> 5, q = (k >> 3) & 3, j = k & 7;
            int lane = q * 16 + (n & 15);
            int idx = ((kk * 8 + (n >> 4)) * 64 + lane) * 8 + j;
            Vf[obase + idx] = bf16rn(w);
        }
        return;
    }
    blk -= vBlocks;
    int i = blk * blockDim.x + threadIdx.x;
    if (i < E) atomicAdd(&cnt[dst[i]], 1);
}

// ---------------- counting-sort scan (2 kernels) ----------------

__global__ void scan_partial(const int* __restrict__ cnt, int N,
                             int* __restrict__ excl, int* __restrict__ bsum) {
    __shared__ int s[SCAN_B];
    int t = threadIdx.x, i = blockIdx.x * SCAN_B + t;
    int v = (i < N) ? cnt[i] : 0;
    s[t] = v; __syncthreads();
    for (int o = 1; o < SCAN_B; o <<= 1) {
        int x = (t >= o) ? s[t - o] : 0;
        __syncthreads();
        s[t] += x;
        __syncthreads();
    }
    if (i < N) excl[i] = s[t] - v;
    if (t == SCAN_B - 1) bsum[blockIdx.x] = s[t];
}

// adds block-sum prefix (computed in-wave, nb<=64) and inits cursor
__global__ void scan_fixup(int* __restrict__ row_ptr, const int* __restrict__ bsum,
                           int nb, int N, int E, int* __restrict__ cursor) {
    __shared__ int pref[64];
    int t = threadIdx.x;
    if (t < 64) {
        int raw = (t < nb) ? bsum[t] : 0;
        int v = raw;
#pragma unroll
        for (int o = 1; o < 64; o <<= 1) {
            int u = __shfl_up(v, o, 64);
            if (t >= o) v += u;
        }
        pref[t] = v - raw;     // exclusive prefix
    }
    __syncthreads();
    int i = blockIdx.x * blockDim.x + t;
    if (i < N) { int val = row_ptr[i] + pref[i >> 10]; row_ptr[i] = val; cursor[i] = val; }
    if (i == 0) row_ptr[N] = E;
}

// pack (etype, src) into one int: src < 65536
__global__ void scatter_dst(const int* __restrict__ dst, const int* __restrict__ src,
                            const int* __restrict__ et, const float* __restrict__ norm,
                            int E, int* __restrict__ cursor, int2* __restrict__ edata) {
    int i = blockIdx.x * blockDim.x + threadIdx.x;
    if (i >= E) return;
    int p = atomicAdd(&cursor[dst[i]], 1);
    edata[p] = make_int2((et[i] << 16) | src[i], __float_as_int(norm[i]));
}

// ---------------- fused per-tile RGCN layer (round-4 winner + pinned waves/EU) ----------------
// Block = 32 dst rows, 512 threads (8 waves). Phase A (quarter-wave row-parallel):
// quarter q of wave w owns dst row 4w+q; lane l16 covers the row's words 4*l16..+3,
// so ONE dwordx4 gather carries 4 edges. edata ping-pong 2-deep via named regs.
// KEY CHANGE vs round 4: __launch_bounds__(512,4) left waves-per-EU max unbounded, so
// the allocator squeezed toward 8 waves/SIMD, split the unified regfile ~half/half
// (VGPR_Count 56/32/64 at rounds 4/5/6), parked the 64-float acc in AGPRs, and wrapped
// every v_pk_fma in v_accvgpr_read/write (~3-4x VALU -- the measured VALU time is ~4x
// the algorithmic count). amdgpu_waves_per_eu(4,4) pins min=max=4 -> budget exactly
// 128 regs/wave -> acc (64) + working (~30) fit as arch VGPRs, no copies. Occupancy is
// LDS-bound (66 KB -> 2 blocks/CU = 4 waves/SIMD) so nothing is lost.
// Phase B: Z(32x1024) @ V(1024x128); B-frags from L2-resident Vf; wave = t-tile x 2 m.
// mode 0: store bf16(relu(acc+bias)); mode 1: store fp32(acc+bias).

__global__ __launch_bounds__(512)
__attribute__((amdgpu_waves_per_eu(4, 4)))
void rgcn_tile(
    const unsigned* __restrict__ hb, const int2* __restrict__ edata,
    const int* __restrict__ row_ptr, const float* __restrict__ coef,
    const short* __restrict__ Vf, const float* __restrict__ bias,
    void* __restrict__ outp, int N, int E, int mode) {
    __shared__ __align__(16) unsigned Zs[N_BASES][4][4][ROWS + 1][4];  // 66 KB
    __shared__ __align__(16) float cofs[N_RELS * N_BASES];             // 512 B

    const int tid = threadIdx.x;
    const int wave = tid >> 6, lane = tid & 63;
    const int l16 = lane & 15;
    const int nb0 = blockIdx.x * ROWS;

    if (tid < N_RELS * N_BASES) cofs[tid] = coef[tid];
    __syncthreads();

    // quarter q of wave w owns local row r = tid>>4 (0..31)
    const int r = tid >> 4;
    const int node = nb0 + r;
    const int cn = (node < N) ? node : (N - 1);
    const int s = row_ptr[cn];
    const int len = (node < N) ? (row_ptr[cn + 1] - s) : 0;

    // wave-uniform trip count = max len over the wave's 4 quarters
    int mx = len;
    mx = max(mx, __shfl_xor(mx, 16, 64));
    mx = max(mx, __shfl_xor(mx, 32, 64));
    const int nG = __builtin_amdgcn_readfirstlane(mx);

    floatx2 acc[4][N_BASES] = {};   // [word c][base b], statically indexed only

    auto edix = [&](int j) { int ix = s + j; return (ix > E - 1) ? (E - 1) : ix; };
    auto gath = [&](int2 m) {
        return ((const uint4*)(hb + (size_t)(m.x & 0xffff) * 64))[l16];
    };
    auto procG = [&](int2 m, uint4 g, int j) {
        float nv = (j < len) ? __int_as_float(m.y) : 0.f;
        int ets = m.x >> 16;                               // always valid 0..15
        floatx4 c0 = *(const floatx4*)&cofs[ets * 8];      // ds_read_b128 x2
        floatx4 c1 = *(const floatx4*)&cofs[ets * 8 + 4];
        floatx2 v0, v1, v2, v3;
        v0.x = __uint_as_float(g.x << 16) * nv; v0.y = __uint_as_float(g.x & 0xffff0000u) * nv;
        v1.x = __uint_as_float(g.y << 16) * nv; v1.y = __uint_as_float(g.y & 0xffff0000u) * nv;
        v2.x = __uint_as_float(g.z << 16) * nv; v2.y = __uint_as_float(g.z & 0xffff0000u) * nv;
        v3.x = __uint_as_float(g.w << 16) * nv; v3.y = __uint_as_float(g.w & 0xffff0000u) * nv;
#pragma unroll
        for (int b = 0; b < N_BASES; b++) {
            float cw = (b < 4) ? c0[b & 3] : c1[b & 3];
            acc[0][b] = v0 * cw + acc[0][b];
            acc[1][b] = v1 * cw + acc[1][b];
            acc[2][b] = v2 * cw + acc[2][b];
            acc[3][b] = v3 * cw + acc[3][b];
        }
    };

    // 2-deep ping-pong: named regs only (register-array copies force vmcnt drains)
    int2 m0 = edata[edix(0)];
    uint4 g0 = gath(m0);
    int2 m1 = edata[edix(1)];

    int k = 0;
    for (; k + 2 <= nG; k += 2) {
        uint4 g1 = gath(m1);          // gather k+1 (m1 loaded >=1 iter ago)
        procG(m0, g0, k);             // waits g0 only (older in FIFO)
        m0 = edata[edix(k + 2)];
        g0 = gath(m0);                // gather k+2
        procG(m1, g1, k + 1);
        m1 = edata[edix(k + 3)];
    }
    if (k < nG) procG(m0, g0, k);     // nG-k <= 1

    // flush: lane (q,l16) owns row r, words 4*l16+c -> frag coords ((l16>>2),(l16&3),c)
    {
        uint4 w;
#pragma unroll
        for (int b = 0; b < N_BASES; b++) {
            w.x = packbf2(acc[0][b]);
            w.y = packbf2(acc[1][b]);
            w.z = packbf2(acc[2][b]);
            w.w = packbf2(acc[3][b]);
            *(uint4*)&Zs[b][l16 >> 2][l16 & 3][r][0] = w;
        }
    }
    __syncthreads();

    // ---- phase B: wave owns t-tile tt=wave, m-tiles {0,1}
    const int q = lane >> 4, cc = lane & 15;
    const int tt = wave;
    floatx4 ac0 = {}, ac1 = {};

#pragma unroll 2
    for (int b = 0; b < N_BASES; b++) {
#pragma unroll
        for (int kk = 0; kk < 4; kk++) {
            bf16x8 a = *(const bf16x8*)&Zs[b][kk][q][cc][0];
            bf16x8 am = *(const bf16x8*)&Zs[b][kk][q][16 + cc][0];
            bf16x8 B = *(const bf16x8*)(Vf + (size_t)b * 16384 +
                                        ((size_t)(kk * 8 + tt) * 64 + lane) * 8);
            ac0 = __builtin_amdgcn_mfma_f32_16x16x32_bf16(a, B, ac0, 0, 0, 0);
            ac1 = __builtin_amdgcn_mfma_f32_16x16x32_bf16(am, B, ac1, 0, 0, 0);
        }
    }

    // ---- epilogue: C/D layout col = tt*16+cc, row(m) = mi*16 + q*4+i
    float bv = bias[tt * 16 + cc];
    if (mode == 0) {
        unsigned short* o = (unsigned short*)outp;
#pragma unroll
        for (int mi = 0; mi < 2; mi++) {
            const floatx4& c = mi ? ac1 : ac0;
#pragma unroll
            for (int i = 0; i < 4; i++) {
                int nd = nb0 + mi * 16 + q * 4 + i;
                if (nd < N) {
                    float v = fmaxf(c[i] + bv, 0.f);
                    o[(size_t)nd * HD + tt * 16 + cc] = (unsigned short)bf16rn(v);
                }
            }
        }
    } else {
        float* o = (float*)outp;
#pragma unroll
        for (int mi = 0; mi < 2; mi++) {
            const floatx4& c = mi ? ac1 : ac0;
#pragma unroll
            for (int i = 0; i < 4; i++) {
                int nd = nb0 + mi * 16 + q * 4 + i;
                if (nd < N) o[(size_t)nd * HD + tt * 16 + cc] = c[i] + bv;
            }
        }
    }
}

// ---------------- launch ----------------

extern "C" void kernel_launch(void* const* d_in, const int* in_sizes, int n_in,
                              void* d_out, int out_size, void* d_ws, size_t ws_size,
                              hipStream_t stream) {
    const float* h     = (const float*)d_in[0];
    const float* norm  = (const float*)d_in[1];
    const int*   src   = (const int*)d_in[2];
    const int*   dst   = (const int*)d_in[3];
    const int*   etype = (const int*)d_in[4];
    const float* V1    = (const float*)d_in[5];
    const float* coef1 = (const float*)d_in[6];
    const float* bias1 = (const float*)d_in[7];
    const float* V2    = (const float*)d_in[8];
    const float* coef2 = (const float*)d_in[9];
    const float* bias2 = (const float*)d_in[10];
    const int N = in_sizes[0] / HD;   // 50000
    const int E = in_sizes[2];        // 640000
    float* out = (float*)d_out;
    (void)n_in; (void)out_size; (void)ws_size;

    char* ws = (char*)d_ws;
    size_t off = 0;
    auto alloc = [&](size_t bytes) {
        void* p = ws + off;
        off += (bytes + 255) & ~(size_t)255;
        return p;
    };
    short*    Vf      = (short*)alloc((size_t)16 * 16384 * sizeof(short));   // 512 KB
    unsigned* hb      = (unsigned*)alloc((size_t)N * 64 * sizeof(unsigned)); // 12.8 MB
    unsigned* h1b     = (unsigned*)alloc((size_t)N * 64 * sizeof(unsigned)); // 12.8 MB
    int2*     edata   = (int2*)alloc((size_t)E * sizeof(int2));
    int*      cnt     = (int*)alloc((size_t)N * sizeof(int));
    int*      row_ptr = (int*)alloc((size_t)(N + 1) * sizeof(int));
    int*      cursor  = (int*)alloc((size_t)N * sizeof(int));
    int*      bsum    = (int*)alloc(256 * sizeof(int));

    const int nb = (N + SCAN_B - 1) / SCAN_B;                 // 49
    const int packBlocks = (N * 32 + 255) / 256;              // 6250 (float4 pack)
    const int vBlocks = 16;
    const int histBlocks = (E + 255) / 256;                   // 2500

    hipMemsetAsync(cnt, 0, (size_t)N * sizeof(int), stream);
    setup_fused<<<packBlocks + vBlocks + histBlocks, 256, 0, stream>>>(
        h, hb, N * 32, V1, V2, Vf, dst, E, cnt, packBlocks, vBlocks);
    scan_partial<<<nb, SCAN_B, 0, stream>>>(cnt, N, row_ptr, bsum);
    scan_fixup<<<(N + 255) / 256, 256, 0, stream>>>(row_ptr, bsum, nb, N, E, cursor);
    scatter_dst<<<(E + 255) / 256, 256, 0, stream>>>(dst, src, etype, norm, E, cursor, edata);

    const int tiles = (N + ROWS - 1) / ROWS;   // 1563

    // layer 1: h1b = bf16(relu(bias1 + Z @ V1))
    rgcn_tile<<<tiles, 512, 0, stream>>>(hb, edata, row_ptr, coef1, Vf, bias1, h1b, N, E, 0);
    // layer 2: out = bias2 + Z(h1b) @ V2
    rgcn_tile<<<tiles, 512, 0, stream>>>(h1b, edata, row_ptr, coef2, Vf + (size_t)8 * 16384,
                                         bias2, out, N, E, 1);
}